// Round 9
// baseline (5115.121 us; speedup 1.0000x reference)
//
#include <hip/hip_runtime.h>
#include <math.h>

// Neural Additive Model: 256 per-feature MLPs 1->128->64->32->1 (ReLU), summed.
// B=8192, fp32 in/out.
//
// Exact rank-table decomposition: pre-relu h2[b,k] = x_b*Sw[r,k] + Sb[r,k],
// r = #(sorted layer-1 thresholds < x_b) (monotone in x). Layers 2-relu/3/4 explicit.
//
// Round 9:
//  * Layer 3 on bf16 MFMA (16x16x32): wave-round = 16 batch elems, 4 chained
//    mfmas (2 k-tiles x 2 n-tiles). Kills the 2048 scalar-fma/elem VALU floor
//    (~77 us) that rounds 3-8 were pinned at. fp32 accumulate; bf16 rounding
//    of h2/W3 est. ~5e-3 total (threshold 5.75e-2).
//  * build_tables FUSED into main (table built in LDS, never hits global):
//    kills 34 MB round-trip + a launch (the stable ~82 us "rest").
//  * Table rank-major, row = 64 (Sw,Sb) pairs padded to 33 float4 (odd ->
//    spreads 4-bank groups); lane's 8 k-pairs contiguous -> 8 ds_read_b128
//    per 16-elem round (half the LDS instrs of round 8).
//  * Epilogue: per-lane atomicAdd (16 lanes/address) instead of shfl-reduce,
//    keeping the reduction off the (bottleneck) LDS pipe.

#define NF   256
#define NH1  128
#define NH2  64
#define NH3  32
#define NB   8192

#define NRANK 129
#define SROW4 33                     // float4 per table row (132 floats, odd f4 count)

typedef float f32x4 __attribute__((ext_vector_type(4)));
typedef short s16x8 __attribute__((ext_vector_type(8)));

// float -> bf16 bits, round-to-nearest-even
__device__ __forceinline__ short f2bf(float f) {
    unsigned int u = __float_as_uint(f);
    u += 0x7FFFu + ((u >> 16) & 1u);
    return (short)(u >> 16);
}

__global__ __launch_bounds__(256) void init_out_kernel(float* __restrict__ out,
                                                       const float* __restrict__ bias) {
    int i = blockIdx.x * 256 + threadIdx.x;
    if (i < NB) out[i] = bias[0];
}

// ---------------- x transpose: x[b][f] -> xT[f][b], 64x64 LDS tiles ----------------
__global__ __launch_bounds__(256) void transpose_x(const float* __restrict__ x,
                                                   float* __restrict__ xT) {
    __shared__ float tile[64][65];
    const int bf = blockIdx.x & 3;          // f tile (256/64)
    const int bb = blockIdx.x >> 2;         // b tile (8192/64)
    const int tx = threadIdx.x & 63, ty = threadIdx.x >> 6;
    const int f0 = bf * 64, b0 = bb * 64;
    #pragma unroll
    for (int i = 0; i < 16; ++i) {
        int row = i * 4 + ty;
        tile[row][tx] = x[(size_t)(b0 + row) * NF + f0 + tx];   // coalesced read
    }
    __syncthreads();
    #pragma unroll
    for (int i = 0; i < 16; ++i) {
        int row = i * 4 + ty;
        xT[(size_t)(f0 + row) * NB + b0 + tx] = tile[tx][row];  // coalesced write
    }
}

// ---------------- fused: build table in LDS, then MFMA main loop ----------------
template <bool USE_XT>
__global__ __launch_bounds__(1024, 4) void nam_fused(
    const float* __restrict__ x,      // [B][F] (fallback)
    const float* __restrict__ xT,     // [F][B] (preferred)
    const float* __restrict__ W1, const float* __restrict__ b1,
    const float* __restrict__ W2, const float* __restrict__ b2,
    const float* __restrict__ W3, const float* __restrict__ b3,
    const float* __restrict__ W4, const float* __restrict__ b4,
    float* __restrict__ out)
{
    __shared__ f32x4 SP4[NRANK * SROW4];   // 68.1 KB rank-major: row r = 64 (Sw,Sb) pairs
    __shared__ float w2s[NH1 * NH2];       // 32 KB  W2[f] staged (build phase only)
    __shared__ float tkey[NH1];            // sorted thresholds (search keys)
    __shared__ int   tidx[NH1];
    __shared__ float w1s[NH1], b1s[NH1];
    __shared__ float Pbw[8][NH2], Pbb[8][NH2], Pdw[8][NH2], Pdb[8][NH2]; // 8 KB partials

    const int f = blockIdx.x;              // one feature per block
    const int t = (int)threadIdx.x;
    float* SPl = (float*)SP4;

    // ======== Phase A: build the rank table in LDS ========
    {
        const float4* w2g = (const float4*)(W2 + (size_t)f * NH1 * NH2);
        float4* w2l = (float4*)w2s;
        for (int i = t; i < NH1 * NH2 / 4; i += 1024) w2l[i] = w2g[i];
    }
    if (t < NH1) {
        float w  = W1[f * NH1 + t];
        float bb = b1[f * NH1 + t];
        w1s[t] = w; b1s[t] = bb;
        tkey[t] = (w != 0.0f) ? (-bb / w) : INFINITY;   // w==0: never toggled
        tidx[t] = t;
    }
    __syncthreads();

    // bitonic sort of 128 (key asc, payload idx); 64 comparators
    for (int size = 2; size <= NH1; size <<= 1) {
        for (int stride = size >> 1; stride > 0; stride >>= 1) {
            if (t < 64) {
                int pos = ((t / stride) * (stride << 1)) + (t % stride);
                int par = pos + stride;
                bool up = ((pos & size) == 0);
                float a = tkey[pos], c = tkey[par];
                int  ia = tidx[pos], ic = tidx[par];
                if ((a > c) == up) {
                    tkey[pos] = c; tkey[par] = a;
                    tidx[pos] = ic; tidx[par] = ia;
                }
            }
            __syncthreads();
        }
    }

    // chunked scan: 512 threads = (k = t&63) x (chunk c = t>>6, 16 j/ranks each)
    if (t < 512) {
        const int k = t & 63, c = t >> 6;
        float bw = 0.0f, bbp = 0.0f, dw = 0.0f, db = 0.0f;
        #pragma unroll 4
        for (int i = 0; i < 16; ++i) {
            // rank-0 base partial over j in this chunk: w<0 active; w==0&&b>0 const-on
            int j = c * 16 + i;
            float w = w1s[j], bv = b1s[j], w2v = w2s[j * NH2 + k];
            if (w < 0.0f) { bw = fmaf(w, w2v, bw); bbp = fmaf(bv, w2v, bbp); }
            else if (w == 0.0f && bv > 0.0f) { bbp = fmaf(bv, w2v, bbp); }
            // toggle-delta partial over ranks in this chunk
            int jj = tidx[c * 16 + i];
            float ww = w1s[jj], bv2 = b1s[jj], w2x = w2s[jj * NH2 + k];
            float s = (ww > 0.0f) ? 1.0f : ((ww < 0.0f) ? -1.0f : 0.0f);
            dw = fmaf(s * ww,  w2x, dw);
            db = fmaf(s * bv2, w2x, db);
        }
        Pbw[c][k] = bw; Pbb[c][k] = bbp; Pdw[c][k] = dw; Pdb[c][k] = db;
    }
    __syncthreads();
    if (t < 512) {
        const int k = t & 63, c = t >> 6;
        // start acc = b2 + full rank-0 base + deltas of preceding chunks
        float accw = 0.0f;
        float accb = b2[f * NH2 + k];
        #pragma unroll
        for (int c2 = 0; c2 < 8; ++c2) { accw += Pbw[c2][k]; accb += Pbb[c2][k]; }
        for (int c2 = 0; c2 < c; ++c2) { accw += Pdw[c2][k]; accb += Pdb[c2][k]; }
        if (c == 0) { SPl[2 * k] = accw; SPl[2 * k + 1] = accb; }   // rank-0 row
        #pragma unroll 4
        for (int i = 0; i < 16; ++i) {
            int r = c * 16 + i;
            int j = tidx[r];                       // uniform per chunk -> broadcast
            float w = w1s[j], bv = b1s[j], w2v = w2s[j * NH2 + k];
            float s = (w > 0.0f) ? 1.0f : ((w < 0.0f) ? -1.0f : 0.0f);
            accw = fmaf(s * w,  w2v, accw);
            accb = fmaf(s * bv, w2v, accb);
            SPl[(r + 1) * 132 + 2 * k]     = accw;
            SPl[(r + 1) * 132 + 2 * k + 1] = accb;
        }
    }
    __syncthreads();

    // ======== Phase B: MFMA main loop ========
    const int lane = t & 63, wv = t >> 6;   // 16 waves
    const int m = lane & 15, q = lane >> 4; // batch-row-in-tile, quad
    const int n = m;                        // output column id for B/C/D frags

    // B fragments + per-lane constants (once per wave)
    const float* __restrict__ w3g = W3 + f * NH2 * NH3;
    s16x8 bk0n0, bk0n1, bk1n0, bk1n1;
    #pragma unroll
    for (int j = 0; j < 8; ++j) {
        int k = q * 8 + j;                  // B[k][n]: k = quad*8+j, n = lane&15
        bk0n0[j] = f2bf(w3g[k * NH3 + n]);
        bk0n1[j] = f2bf(w3g[k * NH3 + n + 16]);
        bk1n0[j] = f2bf(w3g[(k + 32) * NH3 + n]);
        bk1n1[j] = f2bf(w3g[(k + 32) * NH3 + n + 16]);
    }
    const float b3n   = b3[f * NH3 + n],  b3n16 = b3[f * NH3 + n + 16];
    const float w4n   = W4[f * NH3 + n],  w4n16 = W4[f * NH3 + n + 16];
    const float badd  = (n == 0) ? b4[f] : 0.0f;   // b4 added once per row
    const float* __restrict__ xcol = xT + (size_t)f * NB;

    #pragma unroll 1
    for (int round = 0; round < 32; ++round) {
        const int base = (round * 16 + wv) * 16;   // 16-elem batch tile
        const int b = base + m;
        const float xv = USE_XT ? xcol[b] : x[(size_t)b * NF + f];

        // rank = #(tkey < xv), branchless binary search (LDS, 16 distinct addrs)
        int r = 0;
        #pragma unroll
        for (int s = 64; s > 0; s >>= 1)
            if (tkey[r + s - 1] < xv) r += s;

        // gather this lane's 16 (Sw,Sb) pairs: k = q*8..q*8+7 and +32, row r
        const int ro = r * SROW4 + q * 4;
        f32x4 L0 = SP4[ro + 0],  L1 = SP4[ro + 1],  L2 = SP4[ro + 2],  L3 = SP4[ro + 3];
        f32x4 M0 = SP4[ro + 16], M1 = SP4[ro + 17], M2 = SP4[ro + 18], M3 = SP4[ro + 19];

        // h2 = relu(x*Sw+Sb) -> bf16 A-frags (A[m][k = quad*8+j])
        s16x8 a0, a1;
        a0[0] = f2bf(fmaxf(fmaf(xv, L0.x, L0.y), 0.0f));
        a0[1] = f2bf(fmaxf(fmaf(xv, L0.z, L0.w), 0.0f));
        a0[2] = f2bf(fmaxf(fmaf(xv, L1.x, L1.y), 0.0f));
        a0[3] = f2bf(fmaxf(fmaf(xv, L1.z, L1.w), 0.0f));
        a0[4] = f2bf(fmaxf(fmaf(xv, L2.x, L2.y), 0.0f));
        a0[5] = f2bf(fmaxf(fmaf(xv, L2.z, L2.w), 0.0f));
        a0[6] = f2bf(fmaxf(fmaf(xv, L3.x, L3.y), 0.0f));
        a0[7] = f2bf(fmaxf(fmaf(xv, L3.z, L3.w), 0.0f));
        a1[0] = f2bf(fmaxf(fmaf(xv, M0.x, M0.y), 0.0f));
        a1[1] = f2bf(fmaxf(fmaf(xv, M0.z, M0.w), 0.0f));
        a1[2] = f2bf(fmaxf(fmaf(xv, M1.x, M1.y), 0.0f));
        a1[3] = f2bf(fmaxf(fmaf(xv, M1.z, M1.w), 0.0f));
        a1[4] = f2bf(fmaxf(fmaf(xv, M2.x, M2.y), 0.0f));
        a1[5] = f2bf(fmaxf(fmaf(xv, M2.z, M2.w), 0.0f));
        a1[6] = f2bf(fmaxf(fmaf(xv, M3.x, M3.y), 0.0f));
        a1[7] = f2bf(fmaxf(fmaf(xv, M3.z, M3.w), 0.0f));

        // layer 3: D[m][n] = H2 x W3 (+b3), fp32 acc; C/D col=lane&15, row=quad*4+reg
        f32x4 acc0 = {b3n,   b3n,   b3n,   b3n};
        f32x4 acc1 = {b3n16, b3n16, b3n16, b3n16};
        acc0 = __builtin_amdgcn_mfma_f32_16x16x32_bf16(a0, bk0n0, acc0, 0, 0, 0);
        acc0 = __builtin_amdgcn_mfma_f32_16x16x32_bf16(a1, bk1n0, acc0, 0, 0, 0);
        acc1 = __builtin_amdgcn_mfma_f32_16x16x32_bf16(a0, bk0n1, acc1, 0, 0, 0);
        acc1 = __builtin_amdgcn_mfma_f32_16x16x32_bf16(a1, bk1n1, acc1, 0, 0, 0);

        // layer 4 partial + feature-sum: each lane adds its 2-column share
        #pragma unroll
        for (int i = 0; i < 4; ++i) {
            float p = fmaxf(acc0[i], 0.0f) * w4n
                    + fmaxf(acc1[i], 0.0f) * w4n16 + badd;
            atomicAdd(&out[base + q * 4 + i], p);
        }
    }
}

extern "C" void kernel_launch(void* const* d_in, const int* in_sizes, int n_in,
                              void* d_out, int out_size, void* d_ws, size_t ws_size,
                              hipStream_t stream) {
    const float* x    = (const float*)d_in[0];
    const float* W1   = (const float*)d_in[1];
    const float* b1   = (const float*)d_in[2];
    const float* W2   = (const float*)d_in[3];
    const float* b2   = (const float*)d_in[4];
    const float* W3   = (const float*)d_in[5];
    const float* b3   = (const float*)d_in[6];
    const float* W4   = (const float*)d_in[7];
    const float* b4   = (const float*)d_in[8];
    const float* bias = (const float*)d_in[9];
    float* out = (float*)d_out;
    float* xT  = (float*)d_ws;

    const size_t xt_bytes = (size_t)NB * NF * sizeof(float);   // 8.4 MB
    const bool use_xt = (ws_size >= xt_bytes);                 // constant per run

    init_out_kernel<<<NB / 256, 256, 0, stream>>>(out, bias);
    if (use_xt) {
        transpose_x<<<(NB / 64) * (NF / 64), 256, 0, stream>>>(x, xT);
        nam_fused<true><<<NF, 1024, 0, stream>>>(x, xT, W1, b1, W2, b2,
                                                 W3, b3, W4, b4, out);
    } else {
        nam_fused<false><<<NF, 1024, 0, stream>>>(x, xT, W1, b1, W2, b2,
                                                  W3, b3, W4, b4, out);
    }
}

// Round 10
// 186.480 us; speedup vs baseline: 27.4299x; 27.4299x over previous
//
#include <hip/hip_runtime.h>
#include <math.h>

// Neural Additive Model: 256 per-feature MLPs 1->128->64->32->1 (ReLU), summed.
// B=8192, fp32 in/out.
//
// Exact rank-table decomposition: pre-relu h2[b,k] = x_b*Sw[r,k] + Sb[r,k],
// r = #(sorted layer-1 thresholds < x_b). Layer 3 on bf16 MFMA, layer 4 fused.
//
// Round 10: FIX round-9's 25x regression. Cause (rocprof): epilogue did 16
// atomicAdds per (feature,element) -> 33.5M atomics, WRITE_SIZE 917 MB,
// VALUBusy 0.64% (machine stalled on the L2 atomic path). Fix: reduce the 16
// n-lane partials in-register (4 x shfl_xor within the 16-lane group) and
// issue ONE atomicAdd per element from the n==0 lane (2.1M atomics total —
// the round-5..8 level that measured 8 MB WRITE_SIZE).
// Everything else unchanged from round 9 (fused table build in LDS, rank-major
// table, 8x ds_read_b128 gather, 4 chained mfma_f32_16x16x32_bf16).

#define NF   256
#define NH1  128
#define NH2  64
#define NH3  32
#define NB   8192

#define NRANK 129
#define SROW4 33                     // float4 per table row (132 floats, odd f4 count)

typedef float f32x4 __attribute__((ext_vector_type(4)));
typedef short s16x8 __attribute__((ext_vector_type(8)));

// float -> bf16 bits, round-to-nearest-even
__device__ __forceinline__ short f2bf(float f) {
    unsigned int u = __float_as_uint(f);
    u += 0x7FFFu + ((u >> 16) & 1u);
    return (short)(u >> 16);
}

__global__ __launch_bounds__(256) void init_out_kernel(float* __restrict__ out,
                                                       const float* __restrict__ bias) {
    int i = blockIdx.x * 256 + threadIdx.x;
    if (i < NB) out[i] = bias[0];
}

// ---------------- x transpose: x[b][f] -> xT[f][b], 64x64 LDS tiles ----------------
__global__ __launch_bounds__(256) void transpose_x(const float* __restrict__ x,
                                                   float* __restrict__ xT) {
    __shared__ float tile[64][65];
    const int bf = blockIdx.x & 3;          // f tile (256/64)
    const int bb = blockIdx.x >> 2;         // b tile (8192/64)
    const int tx = threadIdx.x & 63, ty = threadIdx.x >> 6;
    const int f0 = bf * 64, b0 = bb * 64;
    #pragma unroll
    for (int i = 0; i < 16; ++i) {
        int row = i * 4 + ty;
        tile[row][tx] = x[(size_t)(b0 + row) * NF + f0 + tx];   // coalesced read
    }
    __syncthreads();
    #pragma unroll
    for (int i = 0; i < 16; ++i) {
        int row = i * 4 + ty;
        xT[(size_t)(f0 + row) * NB + b0 + tx] = tile[tx][row];  // coalesced write
    }
}

// ---------------- fused: build table in LDS, then MFMA main loop ----------------
template <bool USE_XT>
__global__ __launch_bounds__(1024, 4) void nam_fused(
    const float* __restrict__ x,      // [B][F] (fallback)
    const float* __restrict__ xT,     // [F][B] (preferred)
    const float* __restrict__ W1, const float* __restrict__ b1,
    const float* __restrict__ W2, const float* __restrict__ b2,
    const float* __restrict__ W3, const float* __restrict__ b3,
    const float* __restrict__ W4, const float* __restrict__ b4,
    float* __restrict__ out)
{
    __shared__ f32x4 SP4[NRANK * SROW4];   // 68.1 KB rank-major: row r = 64 (Sw,Sb) pairs
    __shared__ float w2s[NH1 * NH2];       // 32 KB  W2[f] staged (build phase only)
    __shared__ float tkey[NH1];            // sorted thresholds (search keys)
    __shared__ int   tidx[NH1];
    __shared__ float w1s[NH1], b1s[NH1];
    __shared__ float Pbw[8][NH2], Pbb[8][NH2], Pdw[8][NH2], Pdb[8][NH2]; // 8 KB partials

    const int f = blockIdx.x;              // one feature per block
    const int t = (int)threadIdx.x;
    float* SPl = (float*)SP4;

    // ======== Phase A: build the rank table in LDS ========
    {
        const float4* w2g = (const float4*)(W2 + (size_t)f * NH1 * NH2);
        float4* w2l = (float4*)w2s;
        for (int i = t; i < NH1 * NH2 / 4; i += 1024) w2l[i] = w2g[i];
    }
    if (t < NH1) {
        float w  = W1[f * NH1 + t];
        float bb = b1[f * NH1 + t];
        w1s[t] = w; b1s[t] = bb;
        tkey[t] = (w != 0.0f) ? (-bb / w) : INFINITY;   // w==0: never toggled
        tidx[t] = t;
    }
    __syncthreads();

    // bitonic sort of 128 (key asc, payload idx); 64 comparators
    for (int size = 2; size <= NH1; size <<= 1) {
        for (int stride = size >> 1; stride > 0; stride >>= 1) {
            if (t < 64) {
                int pos = ((t / stride) * (stride << 1)) + (t % stride);
                int par = pos + stride;
                bool up = ((pos & size) == 0);
                float a = tkey[pos], c = tkey[par];
                int  ia = tidx[pos], ic = tidx[par];
                if ((a > c) == up) {
                    tkey[pos] = c; tkey[par] = a;
                    tidx[pos] = ic; tidx[par] = ia;
                }
            }
            __syncthreads();
        }
    }

    // chunked scan: 512 threads = (k = t&63) x (chunk c = t>>6, 16 j/ranks each)
    if (t < 512) {
        const int k = t & 63, c = t >> 6;
        float bw = 0.0f, bbp = 0.0f, dw = 0.0f, db = 0.0f;
        #pragma unroll 4
        for (int i = 0; i < 16; ++i) {
            // rank-0 base partial over j in this chunk: w<0 active; w==0&&b>0 const-on
            int j = c * 16 + i;
            float w = w1s[j], bv = b1s[j], w2v = w2s[j * NH2 + k];
            if (w < 0.0f) { bw = fmaf(w, w2v, bw); bbp = fmaf(bv, w2v, bbp); }
            else if (w == 0.0f && bv > 0.0f) { bbp = fmaf(bv, w2v, bbp); }
            // toggle-delta partial over ranks in this chunk
            int jj = tidx[c * 16 + i];
            float ww = w1s[jj], bv2 = b1s[jj], w2x = w2s[jj * NH2 + k];
            float s = (ww > 0.0f) ? 1.0f : ((ww < 0.0f) ? -1.0f : 0.0f);
            dw = fmaf(s * ww,  w2x, dw);
            db = fmaf(s * bv2, w2x, db);
        }
        Pbw[c][k] = bw; Pbb[c][k] = bbp; Pdw[c][k] = dw; Pdb[c][k] = db;
    }
    __syncthreads();
    if (t < 512) {
        const int k = t & 63, c = t >> 6;
        // start acc = b2 + full rank-0 base + deltas of preceding chunks
        float accw = 0.0f;
        float accb = b2[f * NH2 + k];
        #pragma unroll
        for (int c2 = 0; c2 < 8; ++c2) { accw += Pbw[c2][k]; accb += Pbb[c2][k]; }
        for (int c2 = 0; c2 < c; ++c2) { accw += Pdw[c2][k]; accb += Pdb[c2][k]; }
        if (c == 0) { SPl[2 * k] = accw; SPl[2 * k + 1] = accb; }   // rank-0 row
        #pragma unroll 4
        for (int i = 0; i < 16; ++i) {
            int r = c * 16 + i;
            int j = tidx[r];                       // uniform per chunk -> broadcast
            float w = w1s[j], bv = b1s[j], w2v = w2s[j * NH2 + k];
            float s = (w > 0.0f) ? 1.0f : ((w < 0.0f) ? -1.0f : 0.0f);
            accw = fmaf(s * w,  w2v, accw);
            accb = fmaf(s * bv, w2v, accb);
            SPl[(r + 1) * 132 + 2 * k]     = accw;
            SPl[(r + 1) * 132 + 2 * k + 1] = accb;
        }
    }
    __syncthreads();

    // ======== Phase B: MFMA main loop ========
    const int lane = t & 63, wv = t >> 6;   // 16 waves
    const int m = lane & 15, q = lane >> 4; // batch-row-in-tile, quad
    const int n = m;                        // output column id for B/C/D frags

    // B fragments + per-lane constants (once per wave)
    const float* __restrict__ w3g = W3 + f * NH2 * NH3;
    s16x8 bk0n0, bk0n1, bk1n0, bk1n1;
    #pragma unroll
    for (int j = 0; j < 8; ++j) {
        int k = q * 8 + j;                  // B[k][n]: k = quad*8+j, n = lane&15
        bk0n0[j] = f2bf(w3g[k * NH3 + n]);
        bk0n1[j] = f2bf(w3g[k * NH3 + n + 16]);
        bk1n0[j] = f2bf(w3g[(k + 32) * NH3 + n]);
        bk1n1[j] = f2bf(w3g[(k + 32) * NH3 + n + 16]);
    }
    const float b3n   = b3[f * NH3 + n],  b3n16 = b3[f * NH3 + n + 16];
    const float w4n   = W4[f * NH3 + n],  w4n16 = W4[f * NH3 + n + 16];
    const float b4f   = b4[f];
    const float* __restrict__ xcol = xT + (size_t)f * NB;

    #pragma unroll 1
    for (int round = 0; round < 32; ++round) {
        const int base = (round * 16 + wv) * 16;   // 16-elem batch tile
        const int b = base + m;
        const float xv = USE_XT ? xcol[b] : x[(size_t)b * NF + f];

        // rank = #(tkey < xv), branchless binary search (LDS)
        int r = 0;
        #pragma unroll
        for (int s = 64; s > 0; s >>= 1)
            if (tkey[r + s - 1] < xv) r += s;

        // gather this lane's 16 (Sw,Sb) pairs: k = q*8..q*8+7 and +32, row r
        const int ro = r * SROW4 + q * 4;
        f32x4 L0 = SP4[ro + 0],  L1 = SP4[ro + 1],  L2 = SP4[ro + 2],  L3 = SP4[ro + 3];
        f32x4 M0 = SP4[ro + 16], M1 = SP4[ro + 17], M2 = SP4[ro + 18], M3 = SP4[ro + 19];

        // h2 = relu(x*Sw+Sb) -> bf16 A-frags (A[m][k = quad*8+j])
        s16x8 a0, a1;
        a0[0] = f2bf(fmaxf(fmaf(xv, L0.x, L0.y), 0.0f));
        a0[1] = f2bf(fmaxf(fmaf(xv, L0.z, L0.w), 0.0f));
        a0[2] = f2bf(fmaxf(fmaf(xv, L1.x, L1.y), 0.0f));
        a0[3] = f2bf(fmaxf(fmaf(xv, L1.z, L1.w), 0.0f));
        a0[4] = f2bf(fmaxf(fmaf(xv, L2.x, L2.y), 0.0f));
        a0[5] = f2bf(fmaxf(fmaf(xv, L2.z, L2.w), 0.0f));
        a0[6] = f2bf(fmaxf(fmaf(xv, L3.x, L3.y), 0.0f));
        a0[7] = f2bf(fmaxf(fmaf(xv, L3.z, L3.w), 0.0f));
        a1[0] = f2bf(fmaxf(fmaf(xv, M0.x, M0.y), 0.0f));
        a1[1] = f2bf(fmaxf(fmaf(xv, M0.z, M0.w), 0.0f));
        a1[2] = f2bf(fmaxf(fmaf(xv, M1.x, M1.y), 0.0f));
        a1[3] = f2bf(fmaxf(fmaf(xv, M1.z, M1.w), 0.0f));
        a1[4] = f2bf(fmaxf(fmaf(xv, M2.x, M2.y), 0.0f));
        a1[5] = f2bf(fmaxf(fmaf(xv, M2.z, M2.w), 0.0f));
        a1[6] = f2bf(fmaxf(fmaf(xv, M3.x, M3.y), 0.0f));
        a1[7] = f2bf(fmaxf(fmaf(xv, M3.z, M3.w), 0.0f));

        // layer 3: D[m][n] = H2 x W3 (+b3), fp32 acc; C/D col=lane&15, row=quad*4+reg
        f32x4 acc0 = {b3n,   b3n,   b3n,   b3n};
        f32x4 acc1 = {b3n16, b3n16, b3n16, b3n16};
        acc0 = __builtin_amdgcn_mfma_f32_16x16x32_bf16(a0, bk0n0, acc0, 0, 0, 0);
        acc0 = __builtin_amdgcn_mfma_f32_16x16x32_bf16(a1, bk1n0, acc0, 0, 0, 0);
        acc1 = __builtin_amdgcn_mfma_f32_16x16x32_bf16(a0, bk0n1, acc1, 0, 0, 0);
        acc1 = __builtin_amdgcn_mfma_f32_16x16x32_bf16(a1, bk1n1, acc1, 0, 0, 0);

        // layer 4 partials per lane (its 2 columns), per row i = q*4..q*4+3
        float p0 = fmaxf(acc0[0], 0.0f) * w4n + fmaxf(acc1[0], 0.0f) * w4n16;
        float p1 = fmaxf(acc0[1], 0.0f) * w4n + fmaxf(acc1[1], 0.0f) * w4n16;
        float p2 = fmaxf(acc0[2], 0.0f) * w4n + fmaxf(acc1[2], 0.0f) * w4n16;
        float p3 = fmaxf(acc0[3], 0.0f) * w4n + fmaxf(acc1[3], 0.0f) * w4n16;

        // ROUND-10 FIX: reduce across the 16 n-lanes in-register (masks 1..8
        // stay inside the lane-group since lane = q*16+n), then ONE atomic
        // per element from the n==0 lane. Was: 16 atomics/element -> 33.5M
        // atomics -> 917 MB WRITE_SIZE -> 25x regression.
        #pragma unroll
        for (int off = 1; off < 16; off <<= 1) {
            p0 += __shfl_xor(p0, off);
            p1 += __shfl_xor(p1, off);
            p2 += __shfl_xor(p2, off);
            p3 += __shfl_xor(p3, off);
        }
        if (n == 0) {
            atomicAdd(&out[base + q * 4 + 0], p0 + b4f);
            atomicAdd(&out[base + q * 4 + 1], p1 + b4f);
            atomicAdd(&out[base + q * 4 + 2], p2 + b4f);
            atomicAdd(&out[base + q * 4 + 3], p3 + b4f);
        }
    }
}

extern "C" void kernel_launch(void* const* d_in, const int* in_sizes, int n_in,
                              void* d_out, int out_size, void* d_ws, size_t ws_size,
                              hipStream_t stream) {
    const float* x    = (const float*)d_in[0];
    const float* W1   = (const float*)d_in[1];
    const float* b1   = (const float*)d_in[2];
    const float* W2   = (const float*)d_in[3];
    const float* b2   = (const float*)d_in[4];
    const float* W3   = (const float*)d_in[5];
    const float* b3   = (const float*)d_in[6];
    const float* W4   = (const float*)d_in[7];
    const float* b4   = (const float*)d_in[8];
    const float* bias = (const float*)d_in[9];
    float* out = (float*)d_out;
    float* xT  = (float*)d_ws;

    const size_t xt_bytes = (size_t)NB * NF * sizeof(float);   // 8.4 MB
    const bool use_xt = (ws_size >= xt_bytes);                 // constant per run

    init_out_kernel<<<NB / 256, 256, 0, stream>>>(out, bias);
    if (use_xt) {
        transpose_x<<<(NB / 64) * (NF / 64), 256, 0, stream>>>(x, xT);
        nam_fused<true><<<NF, 1024, 0, stream>>>(x, xT, W1, b1, W2, b2,
                                                 W3, b3, W4, b4, out);
    } else {
        nam_fused<false><<<NF, 1024, 0, stream>>>(x, xT, W1, b1, W2, b2,
                                                  W3, b3, W4, b4, out);
    }
}

// Round 11
// 140.252 us; speedup vs baseline: 36.4710x; 1.3296x over previous
//
#include <hip/hip_runtime.h>
#include <math.h>

// Neural Additive Model: 256 per-feature MLPs 1->128->64->32->1 (ReLU), summed.
// B=8192, fp32 in/out.
//
// Exact rank-table decomposition: pre-relu h2[b,k] = x_b*Sw[r,k] + Sb[r,k],
// r = #(sorted layer-1 thresholds < x_b). Layer 3 on bf16 MFMA, layer 4 fused.
//
// Round 11 (LDS pipe was the wall: 31 DS instrs/round + 1.07e7 conflict cyc):
//  * MFMA role swap: A = W3^T, B = h2 -> D[ch][batch]. Each batch elem's 32
//    channels live in ONE lane column (rows) -> layer-4 reduces in-register;
//    cross-lane sum = 2 shfl_xor (16,32) instead of 16. (-14 DS instrs/round)
//  * Table packed bf16: (Sw,Sb) in one uint32 -> 4 ds_read_b128 gathers/lane
//    instead of 8; conflict cycles ~halve. h2 rounded with +0x8000 and packed
//    pairwise with v_perm_b32 (1 instr). absmax est ~0.03 (thr 5.75e-2).
//  * init_out merged into transpose_x (one fewer launch).

#define NF   256
#define NH1  128
#define NH2  64
#define NH3  32
#define NB   8192

#define NRANK 129
#define ROW4  17                      // uint4 per table row (64 pairs + pad, odd)
#define ROWU  (ROW4 * 4)              // 68 uint32 per row

typedef float    f32x4 __attribute__((ext_vector_type(4)));
typedef short    s16x8 __attribute__((ext_vector_type(8)));
typedef unsigned u32x4 __attribute__((ext_vector_type(4)));

// float -> bf16 bits, round-to-nearest-even (build phase, cheap path)
__device__ __forceinline__ short f2bf(float f) {
    unsigned int u = __float_as_uint(f);
    u += 0x7FFFu + ((u >> 16) & 1u);
    return (short)(u >> 16);
}
// pack two non-negative floats to (bf16(h1)<<16)|bf16(h0), round-half-up
__device__ __forceinline__ unsigned pack2(float h0, float h1) {
    unsigned a = __float_as_uint(h1) + 0x8000u;
    unsigned b = __float_as_uint(h0) + 0x8000u;
    return __builtin_amdgcn_perm(a, b, 0x07060302u);  // hi16(a)<<16 | hi16(b)
}
// unpack packed (Sb<<16|Sw) and evaluate h2 = relu(x*Sw+Sb)
__device__ __forceinline__ float h2eval(unsigned u, float xv) {
    float sw = __uint_as_float(u << 16);
    float sb = __uint_as_float(u & 0xFFFF0000u);
    return fmaxf(fmaf(xv, sw, sb), 0.0f);
}

__global__ __launch_bounds__(256) void init_out_kernel(float* __restrict__ out,
                                                       const float* __restrict__ bias) {
    int i = blockIdx.x * 256 + threadIdx.x;
    if (i < NB) out[i] = bias[0];
}

// ---------------- x transpose (+ out init): x[b][f] -> xT[f][b] ----------------
__global__ __launch_bounds__(256) void transpose_x(const float* __restrict__ x,
                                                   float* __restrict__ xT,
                                                   float* __restrict__ out,
                                                   const float* __restrict__ bias) {
    __shared__ float tile[64][65];
    // fused out-init (out poisoned before every launch)
    const int gid = blockIdx.x * 256 + (int)threadIdx.x;
    if (gid < NB) out[gid] = bias[0];

    const int bf = blockIdx.x & 3;          // f tile (256/64)
    const int bb = blockIdx.x >> 2;         // b tile (8192/64)
    const int tx = threadIdx.x & 63, ty = threadIdx.x >> 6;
    const int f0 = bf * 64, b0 = bb * 64;
    #pragma unroll
    for (int i = 0; i < 16; ++i) {
        int row = i * 4 + ty;
        tile[row][tx] = x[(size_t)(b0 + row) * NF + f0 + tx];   // coalesced read
    }
    __syncthreads();
    #pragma unroll
    for (int i = 0; i < 16; ++i) {
        int row = i * 4 + ty;
        xT[(size_t)(f0 + row) * NB + b0 + tx] = tile[tx][row];  // coalesced write
    }
}

// ---------------- fused: build table in LDS, then MFMA main loop ----------------
template <bool USE_XT>
__global__ __launch_bounds__(1024, 4) void nam_fused(
    const float* __restrict__ x,      // [B][F] (fallback)
    const float* __restrict__ xT,     // [F][B] (preferred)
    const float* __restrict__ W1, const float* __restrict__ b1,
    const float* __restrict__ W2, const float* __restrict__ b2,
    const float* __restrict__ W3, const float* __restrict__ b3,
    const float* __restrict__ W4, const float* __restrict__ b4,
    float* __restrict__ out)
{
    __shared__ u32x4 SP4[NRANK * ROW4];    // 35.1 KB packed-bf16 (Sb<<16|Sw), rank-major
    __shared__ float w2s[NH1 * NH2];       // 32 KB  W2[f] staged (build phase only)
    __shared__ float tkey[NH1];            // sorted thresholds
    __shared__ int   tidx[NH1];
    __shared__ float w1s[NH1], b1s[NH1];
    __shared__ float Pbw[8][NH2], Pbb[8][NH2], Pdw[8][NH2], Pdb[8][NH2]; // 8 KB

    const int f = blockIdx.x;              // one feature per block
    const int t = (int)threadIdx.x;
    unsigned* SPu = (unsigned*)SP4;

    // ======== Phase A: build the rank table in LDS (packed bf16) ========
    {
        const float4* w2g = (const float4*)(W2 + (size_t)f * NH1 * NH2);
        float4* w2l = (float4*)w2s;
        for (int i = t; i < NH1 * NH2 / 4; i += 1024) w2l[i] = w2g[i];
    }
    if (t < NH1) {
        float w  = W1[f * NH1 + t];
        float bb = b1[f * NH1 + t];
        w1s[t] = w; b1s[t] = bb;
        tkey[t] = (w != 0.0f) ? (-bb / w) : INFINITY;   // w==0: never toggled
        tidx[t] = t;
    }
    __syncthreads();

    // bitonic sort of 128 (key asc, payload idx); 64 comparators
    for (int size = 2; size <= NH1; size <<= 1) {
        for (int stride = size >> 1; stride > 0; stride >>= 1) {
            if (t < 64) {
                int pos = ((t / stride) * (stride << 1)) + (t % stride);
                int par = pos + stride;
                bool up = ((pos & size) == 0);
                float a = tkey[pos], c = tkey[par];
                int  ia = tidx[pos], ic = tidx[par];
                if ((a > c) == up) {
                    tkey[pos] = c; tkey[par] = a;
                    tidx[pos] = ic; tidx[par] = ia;
                }
            }
            __syncthreads();
        }
    }

    // chunked scan: 512 threads = (k = t&63) x (chunk c = t>>6, 16 j/ranks each)
    if (t < 512) {
        const int k = t & 63, c = t >> 6;
        float bw = 0.0f, bbp = 0.0f, dw = 0.0f, db = 0.0f;
        #pragma unroll 4
        for (int i = 0; i < 16; ++i) {
            int j = c * 16 + i;    // rank-0 base: w<0 active; w==0&&b>0 const-on
            float w = w1s[j], bv = b1s[j], w2v = w2s[j * NH2 + k];
            if (w < 0.0f) { bw = fmaf(w, w2v, bw); bbp = fmaf(bv, w2v, bbp); }
            else if (w == 0.0f && bv > 0.0f) { bbp = fmaf(bv, w2v, bbp); }
            int jj = tidx[c * 16 + i];   // toggle-delta partial
            float ww = w1s[jj], bv2 = b1s[jj], w2x = w2s[jj * NH2 + k];
            float s = (ww > 0.0f) ? 1.0f : ((ww < 0.0f) ? -1.0f : 0.0f);
            dw = fmaf(s * ww,  w2x, dw);
            db = fmaf(s * bv2, w2x, db);
        }
        Pbw[c][k] = bw; Pbb[c][k] = bbp; Pdw[c][k] = dw; Pdb[c][k] = db;
    }
    __syncthreads();
    if (t < 512) {
        const int k = t & 63, c = t >> 6;
        float accw = 0.0f;
        float accb = b2[f * NH2 + k];    // b2 seed (round-8 lesson)
        #pragma unroll
        for (int c2 = 0; c2 < 8; ++c2) { accw += Pbw[c2][k]; accb += Pbb[c2][k]; }
        for (int c2 = 0; c2 < c; ++c2) { accw += Pdw[c2][k]; accb += Pdb[c2][k]; }
        if (c == 0)
            SPu[k] = ((unsigned)(unsigned short)f2bf(accb) << 16)
                   | (unsigned short)f2bf(accw);            // rank-0 row
        #pragma unroll 4
        for (int i = 0; i < 16; ++i) {
            int r = c * 16 + i;
            int j = tidx[r];                       // uniform per chunk -> broadcast
            float w = w1s[j], bv = b1s[j], w2v = w2s[j * NH2 + k];
            float s = (w > 0.0f) ? 1.0f : ((w < 0.0f) ? -1.0f : 0.0f);
            accw = fmaf(s * w,  w2v, accw);
            accb = fmaf(s * bv, w2v, accb);
            SPu[(r + 1) * ROWU + k] = ((unsigned)(unsigned short)f2bf(accb) << 16)
                                    | (unsigned short)f2bf(accw);
        }
    }
    __syncthreads();

    // ======== Phase B: MFMA main loop (A = W3^T, B = h2) ========
    const int lane = t & 63, wv = t >> 6;   // 16 waves
    const int n = lane & 15, q = lane >> 4; // n = batch-in-tile (B) / ch (A-frag)

    // A-frags: A[m=lane&15][k=quad*8+j] = W3[k][ch]; ch tiles 0 and 16+
    const float* __restrict__ w3g = W3 + f * NH2 * NH3;
    s16x8 aT0lo, aT0hi, aT1lo, aT1hi;
    #pragma unroll
    for (int j = 0; j < 8; ++j) {
        int k = q * 8 + j;
        aT0lo[j] = f2bf(w3g[k * NH3 + n]);
        aT0hi[j] = f2bf(w3g[(k + 32) * NH3 + n]);
        aT1lo[j] = f2bf(w3g[k * NH3 + n + 16]);
        aT1hi[j] = f2bf(w3g[(k + 32) * NH3 + n + 16]);
    }
    // per-lane channel constants: rows q*4+i (acc0) and 16+q*4+i (acc1)
    float b3c[4], b3ch[4], w4c[4], w4ch[4];
    #pragma unroll
    for (int i = 0; i < 4; ++i) {
        b3c[i]  = b3[f * NH3 + q * 4 + i];
        b3ch[i] = b3[f * NH3 + 16 + q * 4 + i];
        w4c[i]  = W4[f * NH3 + q * 4 + i];
        w4ch[i] = W4[f * NH3 + 16 + q * 4 + i];
    }
    const float b4f = b4[f];
    const float* __restrict__ xcol = xT + (size_t)f * NB;

    #pragma unroll 1
    for (int round = 0; round < 32; ++round) {
        const int base = (round * 16 + wv) * 16;   // 16-elem batch tile
        const int b = base + n;
        const float xv = USE_XT ? xcol[b] : x[(size_t)b * NF + f];

        // rank = #(tkey < xv), branchless binary search (LDS)
        int r = 0;
        #pragma unroll
        for (int s = 64; s > 0; s >>= 1)
            if (tkey[r + s - 1] < xv) r += s;

        // gather lane's 16 packed pairs: k = q*8..+7 and 32+q*8..+7, row r
        const int ro = r * ROW4 + q * 2;
        u32x4 U0 = SP4[ro],     U1 = SP4[ro + 1];
        u32x4 U2 = SP4[ro + 8], U3 = SP4[ro + 9];

        // B-frags: B[k=quad*8+j][n=lane&15] = h2[batch n][k]
        u32x4 d0, d1;
        d0.x = pack2(h2eval(U0.x, xv), h2eval(U0.y, xv));
        d0.y = pack2(h2eval(U0.z, xv), h2eval(U0.w, xv));
        d0.z = pack2(h2eval(U1.x, xv), h2eval(U1.y, xv));
        d0.w = pack2(h2eval(U1.z, xv), h2eval(U1.w, xv));
        d1.x = pack2(h2eval(U2.x, xv), h2eval(U2.y, xv));
        d1.y = pack2(h2eval(U2.z, xv), h2eval(U2.w, xv));
        d1.z = pack2(h2eval(U3.x, xv), h2eval(U3.y, xv));
        d1.w = pack2(h2eval(U3.z, xv), h2eval(U3.w, xv));
        s16x8 bf0 = __builtin_bit_cast(s16x8, d0);
        s16x8 bf1 = __builtin_bit_cast(s16x8, d1);

        // layer 3: D[ch][batch] = W3^T x H2^T (+b3); lane: col=batch n, rows=ch q*4+i
        f32x4 acc0 = {b3c[0], b3c[1], b3c[2], b3c[3]};
        f32x4 acc1 = {b3ch[0], b3ch[1], b3ch[2], b3ch[3]};
        acc0 = __builtin_amdgcn_mfma_f32_16x16x32_bf16(aT0lo, bf0, acc0, 0, 0, 0);
        acc0 = __builtin_amdgcn_mfma_f32_16x16x32_bf16(aT0hi, bf1, acc0, 0, 0, 0);
        acc1 = __builtin_amdgcn_mfma_f32_16x16x32_bf16(aT1lo, bf0, acc1, 0, 0, 0);
        acc1 = __builtin_amdgcn_mfma_f32_16x16x32_bf16(aT1hi, bf1, acc1, 0, 0, 0);

        // layer 4: reduce over the lane's OWN 8 channels, then 2 shfls over q
        float p = fmaxf(acc0[0], 0.0f) * w4c[0] + fmaxf(acc1[0], 0.0f) * w4ch[0]
                + fmaxf(acc0[1], 0.0f) * w4c[1] + fmaxf(acc1[1], 0.0f) * w4ch[1]
                + fmaxf(acc0[2], 0.0f) * w4c[2] + fmaxf(acc1[2], 0.0f) * w4ch[2]
                + fmaxf(acc0[3], 0.0f) * w4c[3] + fmaxf(acc1[3], 0.0f) * w4ch[3];
        p += __shfl_xor(p, 16);
        p += __shfl_xor(p, 32);
        if (lane < 16) atomicAdd(&out[base + lane], p + b4f);
    }
}

extern "C" void kernel_launch(void* const* d_in, const int* in_sizes, int n_in,
                              void* d_out, int out_size, void* d_ws, size_t ws_size,
                              hipStream_t stream) {
    const float* x    = (const float*)d_in[0];
    const float* W1   = (const float*)d_in[1];
    const float* b1   = (const float*)d_in[2];
    const float* W2   = (const float*)d_in[3];
    const float* b2   = (const float*)d_in[4];
    const float* W3   = (const float*)d_in[5];
    const float* b3   = (const float*)d_in[6];
    const float* W4   = (const float*)d_in[7];
    const float* b4   = (const float*)d_in[8];
    const float* bias = (const float*)d_in[9];
    float* out = (float*)d_out;
    float* xT  = (float*)d_ws;

    const size_t xt_bytes = (size_t)NB * NF * sizeof(float);   // 8.4 MB
    const bool use_xt = (ws_size >= xt_bytes);                 // constant per run

    if (use_xt) {
        transpose_x<<<(NB / 64) * (NF / 64), 256, 0, stream>>>(x, xT, out, bias);
        nam_fused<true><<<NF, 1024, 0, stream>>>(x, xT, W1, b1, W2, b2,
                                                 W3, b3, W4, b4, out);
    } else {
        init_out_kernel<<<NB / 256, 256, 0, stream>>>(out, bias);
        nam_fused<false><<<NF, 1024, 0, stream>>>(x, xT, W1, b1, W2, b2,
                                                  W3, b3, W4, b4, out);
    }
}